// Round 1
// baseline (1119.943 us; speedup 1.0000x reference)
//
#include <hip/hip_runtime.h>

#define Hc 256
#define Dc 64
#define Tc 49
#define Bc 4800
#define NPc 16384
#define KOUT 12544          // T*H
#define OUTSTRIDE 1228800   // 4800*256

typedef unsigned short u16;
typedef unsigned int u32;
typedef __bf16 bf16x8 __attribute__((ext_vector_type(8)));
typedef float f32x4 __attribute__((ext_vector_type(4)));

__device__ __forceinline__ u16 f2bf(float f){
  u32 u = __builtin_bit_cast(u32, f);
  u += 0x7fffu + ((u >> 16) & 1u);
  return (u16)(u >> 16);
}

__device__ __forceinline__ int swz9(int x){ return x ^ (((x >> 9) & 7) << 4); }
__device__ __forceinline__ int swz7(int x){ return x ^ (((x >> 7) & 7) << 4); }

#define GLDS16(gp, lp) __builtin_amdgcn_global_load_lds((const __attribute__((address_space(1))) void*)(gp), (__attribute__((address_space(3))) void*)(lp), 16, 0, 0)

__device__ __forceinline__ bf16x8 ldsr(const u16* base, int byteoff){
  return *(const bf16x8*)((const char*)base + byteoff);
}
__device__ __forceinline__ f32x4 mfma16(bf16x8 a, bf16x8 b, f32x4 c){
  return __builtin_amdgcn_mfma_f32_16x16x32_bf16(a, b, c, 0, 0, 0);
}
__device__ __forceinline__ f32x4 zero4(){ f32x4 v; v[0]=0.f; v[1]=0.f; v[2]=0.f; v[3]=0.f; return v; }
__device__ __forceinline__ void red16(float& s, float& q){
  #pragma unroll
  for (int m = 1; m < 16; m <<= 1){ s += __shfl_xor(s, m); q += __shfl_xor(q, m); }
}

// ---------------- elementwise f32 -> bf16 converters ----------------
__global__ void cvt_kernel(const float* __restrict__ src, u16* __restrict__ dst, int n){
  int i = (blockIdx.x*256 + threadIdx.x)*4;
  if (i >= n) return;
  float4 v = *(const float4*)(src + i);
  u16 t[4] = {f2bf(v.x), f2bf(v.y), f2bf(v.z), f2bf(v.w)};
  *(uint2*)(dst + i) = *(const uint2*)t;
}

__global__ void procvt_kernel(const float* __restrict__ src, u16* __restrict__ dst){
  int i = (blockIdx.x*256 + threadIdx.x)*4;  // dst has 4864*256 elems, zero-pad tail
  u16 t[4];
  if (i < Bc*Hc){
    float4 v = *(const float4*)(src + i);
    t[0]=f2bf(v.x); t[1]=f2bf(v.y); t[2]=f2bf(v.z); t[3]=f2bf(v.w);
  } else { t[0]=t[1]=t[2]=t[3]=0; }
  *(uint2*)(dst + i) = *(const uint2*)t;
}

// ---------------- masks: sigmoid((pro@w1^T+b1)@w2^T+b2) ----------------
__global__ __launch_bounds__(256) void masks_kernel(const float* __restrict__ pro,
    const float* __restrict__ pc1w, const float* __restrict__ pc1b,
    const float* __restrict__ pc2w, const float* __restrict__ pc2b,
    const float* __restrict__ pr1w, const float* __restrict__ pr1b,
    const float* __restrict__ pr2w, const float* __restrict__ pr2b,
    float* __restrict__ mcls, float* __restrict__ mreg)
{
  __shared__ float rowv[256];
  __shared__ float hv[32];
  const int tid = threadIdx.x, b = blockIdx.x;
  rowv[tid] = pro[(size_t)b*256 + tid];
  __syncthreads();
  for (int br = 0; br < 2; br++){
    const float* w1 = br ? pr1w : pc1w;
    const float* b1 = br ? pr1b : pc1b;
    const float* w2 = br ? pr2w : pc2w;
    const float* b2 = br ? pr2b : pc2b;
    float* outm = br ? mreg : mcls;
    if (tid < 32){
      float s = b1[tid];
      const float* wr = w1 + tid*256;
      for (int k = 0; k < 256; k += 4)
        s += rowv[k]*wr[k] + rowv[k+1]*wr[k+1] + rowv[k+2]*wr[k+2] + rowv[k+3]*wr[k+3];
      hv[tid] = s;
    }
    __syncthreads();
    float s = b2[tid];
    const float* w2r = w2 + tid*32;
    #pragma unroll
    for (int j = 0; j < 32; j++) s += hv[j]*w2r[j];
    outm[(size_t)b*256 + tid] = 1.f/(1.f + expf(-s));
    __syncthreads();
  }
}

// ---------------- GEMM1: params[C][32768] = proB @ dynwB^T + dynb (bf16 out) ----------------
__global__ __launch_bounds__(512) void gemm1_kernel(const u16* __restrict__ proB,
    const u16* __restrict__ dynwB, const float* __restrict__ dynb,
    u16* __restrict__ paramsOut, int b0, int C)
{
  __shared__ u16 smA[128*256];
  __shared__ u16 smB[128*256];
  const int tid = threadIdx.x;
  const int bx = blockIdx.x, by = blockIdx.y;
  const int l = tid & 63, wid = tid >> 6, lr = l & 15, lg = l >> 4;
  const int wm = wid >> 1, wn = wid & 1;
  {
    const char* Ab = (const char*)(proB + (size_t)(b0 + bx*128)*256);
    const char* Bb = (const char*)(dynwB + (size_t)by*128*256);
    #pragma unroll
    for (int p = 0; p < 8; p++){
      int base = (wid + p*8)*1024;
      int lin = base + l*16;
      GLDS16(Ab + swz9(lin), (char*)smA + base);
      GLDS16(Bb + swz9(lin), (char*)smB + base);
    }
  }
  __syncthreads();
  f32x4 acc[2][4];
  #pragma unroll
  for (int i=0;i<2;i++)
    #pragma unroll
    for (int j=0;j<4;j++) acc[i][j] = zero4();
  #pragma unroll
  for (int ks = 0; ks < 8; ks++){
    bf16x8 av[2], bv[4];
    #pragma unroll
    for (int mt = 0; mt < 2; mt++) av[mt] = ldsr(smA, swz9((wm*32 + mt*16 + lr)*512 + ks*64 + lg*16));
    #pragma unroll
    for (int nt = 0; nt < 4; nt++) bv[nt] = ldsr(smB, swz9((wn*64 + nt*16 + lr)*512 + ks*64 + lg*16));
    #pragma unroll
    for (int mt = 0; mt < 2; mt++)
      #pragma unroll
      for (int nt = 0; nt < 4; nt++)
        acc[mt][nt] = mfma16(av[mt], bv[nt], acc[mt][nt]);
  }
  __syncthreads();
  float bbias[4];
  #pragma unroll
  for (int nt = 0; nt < 4; nt++) bbias[nt] = dynb[by*128 + wn*64 + nt*16 + lr];
  #pragma unroll
  for (int mt = 0; mt < 2; mt++)
    #pragma unroll
    for (int nt = 0; nt < 4; nt++)
      #pragma unroll
      for (int r = 0; r < 4; r++){
        int row = wm*32 + mt*16 + lg*4 + r;
        int col = wn*64 + nt*16 + lr;
        ((u16*)smA)[row*128 + col] = f2bf(acc[mt][nt][r] + bbias[nt]);
      }
  __syncthreads();
  #pragma unroll
  for (int p = 0; p < 4; p++){
    int lin = tid*16 + p*8192;
    int row = lin >> 8;
    int cb = lin & 255;
    int rg = bx*128 + row;
    if (rg < C)
      *(uint4*)((char*)paramsOut + (size_t)rg*65536 + (size_t)by*256 + cb) = *(const uint4*)((const char*)smA + lin);
  }
}

// ---------------- convA: x = feats_b @ p1 ; y = relu(LN_D(x)) -> yout[C][64][64] bf16 ----------------
__global__ __launch_bounds__(256) void convA_kernel(const float* __restrict__ roi,
    const u16* __restrict__ params, const float* __restrict__ n1g, const float* __restrict__ n1b,
    u16* __restrict__ yout, int b0)
{
  __shared__ u16 smA[64*256];   // feats bf16, swz9
  __shared__ u16 smB[64*256];   // p1^T [d][h], swz9
  __shared__ float red[64*8];
  __shared__ float mu_s[64], rs_s[64];
  const int tid = threadIdx.x, bloc = blockIdx.x;
  const int b = b0 + bloc;
  const int l = tid & 63, w = tid >> 6, lr = l & 15, lg = l >> 4;
  {
    int tb = tid >> 5;
    int k0 = (tid & 31)*8;
    #pragma unroll
    for (int p = 0; p < 8; p++){
      int row = tb + p*8;
      u16 t[8];
      if (row < Tc){
        const float* s = roi + ((size_t)row*Bc + b)*256 + k0;
        float4 v0 = *(const float4*)s;
        float4 v1 = *(const float4*)(s+4);
        t[0]=f2bf(v0.x); t[1]=f2bf(v0.y); t[2]=f2bf(v0.z); t[3]=f2bf(v0.w);
        t[4]=f2bf(v1.x); t[5]=f2bf(v1.y); t[6]=f2bf(v1.z); t[7]=f2bf(v1.w);
      } else {
        #pragma unroll
        for (int j=0;j<8;j++) t[j]=0;
      }
      *(uint4*)((char*)smA + swz9(row*512 + k0*2)) = *(const uint4*)t;
    }
  }
  {
    const u16* p1 = params + (size_t)bloc*32768;
    int d = tid & 63;
    int hb = (tid >> 6)*8;
    #pragma unroll
    for (int it = 0; it < 8; it++){
      int h0 = hb + it*32;
      u16 t[8];
      #pragma unroll
      for (int j = 0; j < 8; j++) t[j] = p1[(h0+j)*64 + d];
      *(uint4*)((char*)smB + swz9(d*512 + h0*2)) = *(const uint4*)t;
    }
  }
  __syncthreads();
  f32x4 acc[4];
  #pragma unroll
  for (int i=0;i<4;i++) acc[i] = zero4();
  #pragma unroll
  for (int ks = 0; ks < 8; ks++){
    bf16x8 bv = ldsr(smB, swz9((w*16 + lr)*512 + ks*64 + lg*16));
    #pragma unroll
    for (int mt = 0; mt < 4; mt++){
      bf16x8 av = ldsr(smA, swz9((mt*16 + lr)*512 + ks*64 + lg*16));
      acc[mt] = mfma16(av, bv, acc[mt]);
    }
  }
  #pragma unroll
  for (int mt = 0; mt < 4; mt++){
    #pragma unroll
    for (int r = 0; r < 4; r++){
      float v = acc[mt][r];
      float s = v, q = v*v;
      red16(s, q);
      if (lr == 0){
        int row = mt*16 + lg*4 + r;
        red[row*8 + w*2] = s; red[row*8 + w*2 + 1] = q;
      }
    }
  }
  __syncthreads();
  if (tid < 64){
    float s = 0.f, q = 0.f;
    #pragma unroll
    for (int ww = 0; ww < 4; ww++){ s += red[tid*8 + ww*2]; q += red[tid*8 + ww*2 + 1]; }
    float mu = s*(1.f/64.f);
    float var = q*(1.f/64.f) - mu*mu;
    mu_s[tid] = mu; rs_s[tid] = rsqrtf(var + 1e-5f);
  }
  __syncthreads();
  const int dcol = w*16 + lr;
  const float gg = n1g[dcol], gb = n1b[dcol];
  #pragma unroll
  for (int mt = 0; mt < 4; mt++){
    #pragma unroll
    for (int r = 0; r < 4; r++){
      int row = mt*16 + lg*4 + r;
      float v = (acc[mt][r] - mu_s[row])*rs_s[row]*gg + gb;
      ((u16*)smA)[row*64 + dcol] = f2bf(fmaxf(v, 0.f));
    }
  }
  __syncthreads();
  {
    u16* dst = yout + (size_t)bloc*4096;
    int lin = tid*16;
    *(uint4*)((char*)dst + lin) = *(const uint4*)((const char*)smA + lin);
    *(uint4*)((char*)dst + lin + 4096) = *(const uint4*)((const char*)smA + lin + 4096);
  }
}

// ---------------- convB: x2=y@p2; relu(LN2); *mask; relu(LN3) -> fcin/frin bf16 ----------------
__global__ __launch_bounds__(256) void convB_kernel(
    const u16* __restrict__ params, const u16* __restrict__ yin,
    const float* __restrict__ mcls, const float* __restrict__ mreg,
    const float* __restrict__ n2g, const float* __restrict__ n2b,
    const float* __restrict__ n3cg, const float* __restrict__ n3cb,
    const float* __restrict__ n3rg, const float* __restrict__ n3rb,
    u16* __restrict__ fcin, u16* __restrict__ frin, int b0)
{
  __shared__ u16 smY[64*64];    // y, swz7
  __shared__ u16 smP[256*64];   // p2^T [h][d], swz7 ; reused as output tile [64][256]
  __shared__ float red[64*8];
  __shared__ float mu_s[64], rs_s[64], mu2_s[64], rs2_s[64];
  const int tid = threadIdx.x, bloc = blockIdx.x;
  const int b = b0 + bloc;
  const int l = tid & 63, w = tid >> 6, lr = l & 15, lg = l >> 4;
  {
    const char* ybase = (const char*)yin + (size_t)bloc*8192;
    #pragma unroll
    for (int p = 0; p < 2; p++){
      int base = (w + p*4)*1024;
      GLDS16(ybase + swz7(base + l*16), (char*)smY + base);
    }
  }
  {
    const u16* p2 = params + (size_t)bloc*32768 + NPc;
    int h = tid;
    #pragma unroll
    for (int it = 0; it < 8; it++){
      int d0 = it*8;
      u16 t[8];
      #pragma unroll
      for (int j = 0; j < 8; j++) t[j] = p2[(d0+j)*256 + h];
      *(uint4*)((char*)smP + swz7(h*128 + d0*2)) = *(const uint4*)t;
    }
  }
  __syncthreads();
  f32x4 acc[4][4];
  #pragma unroll
  for (int i=0;i<4;i++)
    #pragma unroll
    for (int j=0;j<4;j++) acc[i][j] = zero4();
  #pragma unroll
  for (int ks = 0; ks < 2; ks++){
    bf16x8 av[4], bv[4];
    #pragma unroll
    for (int mt=0; mt<4; mt++) av[mt] = ldsr(smY, swz7((mt*16+lr)*128 + ks*64 + lg*16));
    #pragma unroll
    for (int nt=0; nt<4; nt++) bv[nt] = ldsr(smP, swz7((w*64+nt*16+lr)*128 + ks*64 + lg*16));
    #pragma unroll
    for (int mt=0; mt<4; mt++)
      #pragma unroll
      for (int nt=0; nt<4; nt++)
        acc[mt][nt] = mfma16(av[mt], bv[nt], acc[mt][nt]);
  }
  // LN2 stats (over 256 cols)
  #pragma unroll
  for (int mt=0; mt<4; mt++){
    #pragma unroll
    for (int r=0; r<4; r++){
      float s = acc[mt][0][r]+acc[mt][1][r]+acc[mt][2][r]+acc[mt][3][r];
      float q = acc[mt][0][r]*acc[mt][0][r]+acc[mt][1][r]*acc[mt][1][r]
              + acc[mt][2][r]*acc[mt][2][r]+acc[mt][3][r]*acc[mt][3][r];
      red16(s,q);
      if (lr == 0){
        int row = mt*16 + lg*4 + r;
        red[row*8 + w*2] = s; red[row*8 + w*2 + 1] = q;
      }
    }
  }
  __syncthreads();
  if (tid < 64){
    float s=0.f, q=0.f;
    #pragma unroll
    for (int ww=0; ww<4; ww++){ s += red[tid*8+ww*2]; q += red[tid*8+ww*2+1]; }
    float mu = s * (1.f/256.f);
    float var = q * (1.f/256.f) - mu*mu;
    mu_s[tid] = mu; rs_s[tid] = rsqrtf(var + 1e-5f);
  }
  __syncthreads();

  float g2[4], bb2[4], mvc[4], mvr[4];
  int cols[4];
  #pragma unroll
  for (int nt=0; nt<4; nt++){
    cols[nt] = w*64 + nt*16 + lr;
    g2[nt] = n2g[cols[nt]]; bb2[nt] = n2b[cols[nt]];
    mvc[nt] = mcls[(size_t)b*256 + cols[nt]];
    mvr[nt] = mreg[(size_t)b*256 + cols[nt]];
  }
  u16* tile = (u16*)smP;
  for (int br = 0; br < 2; br++){
    const float* g3p = br ? n3rg : n3cg;
    const float* b3p = br ? n3rb : n3cb;
    float g3[4], b3[4], mv[4];
    #pragma unroll
    for (int nt=0; nt<4; nt++){ g3[nt]=g3p[cols[nt]]; b3[nt]=b3p[cols[nt]]; mv[nt] = br ? mvr[nt] : mvc[nt]; }
    #pragma unroll
    for (int mt=0; mt<4; mt++){
      #pragma unroll
      for (int r=0; r<4; r++){
        int row = mt*16 + lg*4 + r;
        float s=0.f, q=0.f;
        #pragma unroll
        for (int nt=0; nt<4; nt++){
          float x = (acc[mt][nt][r] - mu_s[row]) * rs_s[row] * g2[nt] + bb2[nt];
          x = fmaxf(x, 0.f);
          float u = x * mv[nt];
          s += u; q += u*u;
        }
        red16(s,q);
        if (lr == 0){ red[row*8 + w*2] = s; red[row*8 + w*2 + 1] = q; }
      }
    }
    __syncthreads();
    if (tid < 64){
      float s=0.f,q=0.f;
      #pragma unroll
      for (int ww=0; ww<4; ww++){ s += red[tid*8+ww*2]; q += red[tid*8+ww*2+1]; }
      float mu = s*(1.f/256.f);
      float var = q*(1.f/256.f) - mu*mu;
      mu2_s[tid] = mu; rs2_s[tid] = rsqrtf(var + 1e-5f);
    }
    __syncthreads();
    #pragma unroll
    for (int mt=0; mt<4; mt++){
      #pragma unroll
      for (int r=0; r<4; r++){
        int row = mt*16 + lg*4 + r;
        #pragma unroll
        for (int nt=0; nt<4; nt++){
          float x = (acc[mt][nt][r] - mu_s[row]) * rs_s[row] * g2[nt] + bb2[nt];
          x = fmaxf(x, 0.f);
          float u = x * mv[nt];
          float f = fmaxf((u - mu2_s[row]) * rs2_s[row] * g3[nt] + b3[nt], 0.f);
          tile[row*256 + cols[nt]] = f2bf(f);
        }
      }
    }
    __syncthreads();
    {
      u16* outp = (br ? frin : fcin) + (size_t)bloc * KOUT;
      #pragma unroll
      for (int p = 0; p < 7; p++){
        int lin = tid*16 + p*4096;
        if (lin < Tc*512)
          *(uint4*)((char*)outp + lin) = *(const uint4*)((const char*)tile + lin);
      }
    }
    __syncthreads();
  }
}

// ---------------- outGEMM: out = relu(LN4(fin @ W^T + bias)) -> d_out fp32 ----------------
__global__ __launch_bounds__(256) void outgemm_kernel(
    const u16* __restrict__ fcin, const u16* __restrict__ frin,
    const u16* __restrict__ ocw, const u16* __restrict__ orw,
    const float* __restrict__ ocb, const float* __restrict__ orb,
    const float* __restrict__ n4cg, const float* __restrict__ n4cb,
    const float* __restrict__ n4rg, const float* __restrict__ n4rb,
    float* __restrict__ dout, int b0, int C)
{
  __shared__ u16 smA[64*64];
  __shared__ u16 smB[256*64];
  __shared__ float red[64*8];
  __shared__ float mu_s[64], rs_s[64];
  const int tid = threadIdx.x;
  const int z = blockIdx.y;
  const int m0 = blockIdx.x * 64;
  const u16* A = z ? frin : fcin;
  const u16* W = z ? orw : ocw;
  const float* biasp = z ? orb : ocb;
  const float* g4p = z ? n4rg : n4cg;
  const float* b4p = z ? n4rb : n4cb;
  const int l = tid & 63, w = tid >> 6, lr = l & 15, lg = l >> 4;

  f32x4 acc[4][4];
  #pragma unroll
  for (int i=0;i<4;i++)
    #pragma unroll
    for (int j=0;j<4;j++) acc[i][j] = zero4();

  for (int kt = 0; kt < 196; kt++){
    #pragma unroll
    for (int p = 0; p < 2; p++){
      int base = (w + p*4)*1024;
      int lin = base + l*16;
      int row = lin >> 7, cb = lin & 127;
      int rg = m0 + row; if (rg > C-1) rg = C-1;
      GLDS16((const char*)A + (size_t)rg*25088 + kt*128 + (cb ^ ((row & 7) << 4)), (char*)smA + base);
    }
    #pragma unroll
    for (int p = 0; p < 8; p++){
      int base = (w + p*4)*1024;
      int lin = base + l*16;
      int n = lin >> 7, cb = lin & 127;
      GLDS16((const char*)W + (size_t)n*25088 + kt*128 + (cb ^ ((n & 7) << 4)), (char*)smB + base);
    }
    __syncthreads();
    #pragma unroll
    for (int ks = 0; ks < 2; ks++){
      bf16x8 av[4], bv[4];
      #pragma unroll
      for (int mt=0; mt<4; mt++) av[mt] = ldsr(smA, swz7((mt*16+lr)*128 + ks*64 + lg*16));
      #pragma unroll
      for (int nt=0; nt<4; nt++) bv[nt] = ldsr(smB, swz7((w*64+nt*16+lr)*128 + ks*64 + lg*16));
      #pragma unroll
      for (int mt=0; mt<4; mt++)
        #pragma unroll
        for (int nt=0; nt<4; nt++)
          acc[mt][nt] = mfma16(av[mt], bv[nt], acc[mt][nt]);
    }
    __syncthreads();
  }
  int cols[4]; float bv4[4], g4[4], b4[4];
  #pragma unroll
  for (int nt=0; nt<4; nt++){
    cols[nt] = w*64 + nt*16 + lr;
    bv4[nt] = biasp[cols[nt]]; g4[nt] = g4p[cols[nt]]; b4[nt] = b4p[cols[nt]];
  }
  #pragma unroll
  for (int mt=0; mt<4; mt++){
    #pragma unroll
    for (int r=0; r<4; r++){
      int row = mt*16 + lg*4 + r;
      float s=0.f, q=0.f;
      #pragma unroll
      for (int nt=0; nt<4; nt++){
        float v = acc[mt][nt][r] + bv4[nt];
        s += v; q += v*v;
      }
      red16(s,q);
      if (lr == 0){ red[row*8 + w*2] = s; red[row*8 + w*2 + 1] = q; }
    }
  }
  __syncthreads();
  if (tid < 64){
    float s=0.f,q=0.f;
    #pragma unroll
    for (int ww=0; ww<4; ww++){ s += red[tid*8+ww*2]; q += red[tid*8+ww*2+1]; }
    float mu = s*(1.f/256.f);
    float var = q*(1.f/256.f) - mu*mu;
    mu_s[tid] = mu; rs_s[tid] = rsqrtf(var + 1e-5f);
  }
  __syncthreads();
  #pragma unroll
  for (int mt=0; mt<4; mt++){
    #pragma unroll
    for (int r=0; r<4; r++){
      int row = mt*16 + lg*4 + r;
      if (m0 + row < C){
        #pragma unroll
        for (int nt=0; nt<4; nt++){
          float v = acc[mt][nt][r] + bv4[nt];
          float f = fmaxf((v - mu_s[row])*rs_s[row]*g4[nt] + b4[nt], 0.f);
          dout[(size_t)z*OUTSTRIDE + (size_t)(b0 + m0 + row)*256 + cols[nt]] = f;
        }
      }
    }
  }
}

extern "C" void kernel_launch(void* const* d_in, const int* in_sizes, int n_in,
                              void* d_out, int out_size, void* d_ws, size_t ws_size,
                              hipStream_t stream)
{
  (void)in_sizes; (void)n_in; (void)out_size;
  const float* pro  = (const float*)d_in[0];
  const float* roi  = (const float*)d_in[1];
  const float* dynw = (const float*)d_in[2];
  const float* dynb = (const float*)d_in[3];
  const float* n1g = (const float*)d_in[4];
  const float* n1b = (const float*)d_in[5];
  const float* n2g = (const float*)d_in[6];
  const float* n2b = (const float*)d_in[7];
  const float* pc1w = (const float*)d_in[8];
  const float* pc1b = (const float*)d_in[9];
  const float* pc2w = (const float*)d_in[10];
  const float* pc2b = (const float*)d_in[11];
  const float* n3cg = (const float*)d_in[12];
  const float* n3cb = (const float*)d_in[13];
  const float* pr1w = (const float*)d_in[14];
  const float* pr1b = (const float*)d_in[15];
  const float* pr2w = (const float*)d_in[16];
  const float* pr2b = (const float*)d_in[17];
  const float* n3rg = (const float*)d_in[18];
  const float* n3rb = (const float*)d_in[19];
  const float* ocw = (const float*)d_in[20];
  const float* ocb = (const float*)d_in[21];
  const float* n4cg = (const float*)d_in[22];
  const float* n4cb = (const float*)d_in[23];
  const float* orw = (const float*)d_in[24];
  const float* orb = (const float*)d_in[25];
  const float* n4rg = (const float*)d_in[26];
  const float* n4rb = (const float*)d_in[27];
  float* dout = (float*)d_out;

  char* ws = (char*)d_ws;
  size_t off = 0;
  auto alloc = [&](size_t bytes) -> char* {
    char* p = ws + off;
    off += (bytes + 255) & ~(size_t)255;
    return p;
  };
  u16* dynwB = (u16*)alloc((size_t)32768*256*2);
  u16* ocwB  = (u16*)alloc((size_t)12544*256*2);
  u16* orwB  = (u16*)alloc((size_t)12544*256*2);
  u16* proB  = (u16*)alloc((size_t)4864*256*2);
  float* mcls = (float*)alloc((size_t)4800*256*4);
  float* mreg = (float*)alloc((size_t)4800*256*4);
  size_t fixedOff = off;

  int C = 48;
  const int copts[] = {4800,2400,1600,1200,960,800,600,480,400,300,240,160,120,96,48};
  for (int i = 0; i < (int)(sizeof(copts)/sizeof(int)); i++){
    size_t need = fixedOff + (size_t)copts[i]*(65536 + 8192 + 25088 + 25088) + 8*256;
    if (need <= ws_size){ C = copts[i]; break; }
  }
  u16* paramsC = (u16*)alloc((size_t)C*65536);
  u16* yC      = (u16*)alloc((size_t)C*8192);
  u16* fcinC   = (u16*)alloc((size_t)C*25088);
  u16* frinC   = (u16*)alloc((size_t)C*25088);

  cvt_kernel<<<8192, 256, 0, stream>>>(dynw, dynwB, 32768*256);
  cvt_kernel<<<3136, 256, 0, stream>>>(ocw, ocwB, 12544*256);
  cvt_kernel<<<3136, 256, 0, stream>>>(orw, orwB, 12544*256);
  procvt_kernel<<<1216, 256, 0, stream>>>(pro, proB);
  masks_kernel<<<4800, 256, 0, stream>>>(pro, pc1w, pc1b, pc2w, pc2b,
                                         pr1w, pr1b, pr2w, pr2b, mcls, mreg);
  int nch = 4800 / C;
  for (int c = 0; c < nch; c++){
    int b0 = c*C;
    gemm1_kernel<<<dim3((C+127)/128, 256), 512, 0, stream>>>(proB, dynwB, dynb, paramsC, b0, C);
    convA_kernel<<<C, 256, 0, stream>>>(roi, paramsC, n1g, n1b, yC, b0);
    convB_kernel<<<C, 256, 0, stream>>>(paramsC, yC, mcls, mreg, n2g, n2b,
                                        n3cg, n3cb, n3rg, n3rb, fcinC, frinC, b0);
    outgemm_kernel<<<dim3((C+63)/64, 2), 256, 0, stream>>>(fcinC, frinC, ocwB, orwB,
                                        ocb, orb, n4cg, n4cb, n4rg, n4rb, dout, b0, C);
  }
}

// Round 2
// 756.074 us; speedup vs baseline: 1.4813x; 1.4813x over previous
//
#include <hip/hip_runtime.h>

#define Hc 256
#define Dc 64
#define Tc 49
#define Bc 4800
#define NPc 16384
#define KOUT 12544          // T*H
#define OUTSTRIDE 1228800   // 4800*256

typedef unsigned short u16;
typedef unsigned int u32;
typedef __bf16 bf16x8 __attribute__((ext_vector_type(8)));
typedef float f32x4 __attribute__((ext_vector_type(4)));

__device__ __forceinline__ u16 f2bf(float f){
  u32 u = __builtin_bit_cast(u32, f);
  u += 0x7fffu + ((u >> 16) & 1u);
  return (u16)(u >> 16);
}

#define GLDS16(gp, lp) __builtin_amdgcn_global_load_lds((const __attribute__((address_space(1))) void*)(gp), (__attribute__((address_space(3))) void*)(lp), 16, 0, 0)

__device__ __forceinline__ f32x4 mfma16(bf16x8 a, bf16x8 b, f32x4 c){
  return __builtin_amdgcn_mfma_f32_16x16x32_bf16(a, b, c, 0, 0, 0);
}
__device__ __forceinline__ f32x4 zero4(){ f32x4 v; v[0]=0.f; v[1]=0.f; v[2]=0.f; v[3]=0.f; return v; }

// ---------------- f32 -> bf16 converters ----------------
__global__ void cvt_kernel(const float* __restrict__ src, u16* __restrict__ dst, int n){
  int i = (blockIdx.x*256 + threadIdx.x)*4;
  if (i >= n) return;
  float4 v = *(const float4*)(src + i);
  u16 t[4] = {f2bf(v.x), f2bf(v.y), f2bf(v.z), f2bf(v.w)};
  *(uint2*)(dst + i) = *(const uint2*)t;
}

__global__ void procvt_kernel(const float* __restrict__ src, u16* __restrict__ dst){
  int i = (blockIdx.x*256 + threadIdx.x)*4;  // dst has 4864*256 elems, zero-pad tail
  u16 t[4];
  if (i < Bc*Hc){
    float4 v = *(const float4*)(src + i);
    t[0]=f2bf(v.x); t[1]=f2bf(v.y); t[2]=f2bf(v.z); t[3]=f2bf(v.w);
  } else { t[0]=t[1]=t[2]=t[3]=0; }
  *(uint2*)(dst + i) = *(const uint2*)t;
}

// dynw row-permuted cvt: row n of dyn_w goes to row pi(n) of dynwB so that the
// p1/p2 regions of params land directly in MFMA B-fragment order.
__device__ __forceinline__ int dynperm(int n){
  if (n < NPc){
    int h = n >> 6, d = n & 63;           // p1[h][d], K=h(256), N=d(64)
    return (d>>4)*4096 + (h>>5)*512 + ((h>>3)&3)*128 + (d&15)*8 + (h&7);
  } else {
    int m = n - NPc; int d = m >> 8, h = m & 255;   // p2[d][h], K=d(64), N=h(256)
    return NPc + (h>>4)*1024 + (d>>5)*512 + ((d>>3)&3)*128 + (h&15)*8 + (d&7);
  }
}

__global__ __launch_bounds__(256) void cvt_dynw_perm(const float* __restrict__ dynw,
    const float* __restrict__ dynb, u16* __restrict__ dynwB, float* __restrict__ dynbP){
  int idx = blockIdx.x*256 + threadIdx.x;   // 262144 total: 32768 rows x 8 parts
  int n = idx >> 3, p = idx & 7;
  int pn = dynperm(n);
  const float* s = dynw + (size_t)n*256 + p*32;
  u16 t[32];
  #pragma unroll
  for (int j = 0; j < 8; j++){
    float4 v = *(const float4*)(s + j*4);
    t[j*4+0]=f2bf(v.x); t[j*4+1]=f2bf(v.y); t[j*4+2]=f2bf(v.z); t[j*4+3]=f2bf(v.w);
  }
  u16* d = dynwB + (size_t)pn*256 + p*32;
  #pragma unroll
  for (int j = 0; j < 4; j++) ((uint4*)d)[j] = ((const uint4*)t)[j];
  if (p == 0) dynbP[pn] = dynb[n];
}

// ---------------- masks: sigmoid((pro@w1^T+b1)@w2^T+b2) ----------------
__global__ __launch_bounds__(256) void masks_kernel(const float* __restrict__ pro,
    const float* __restrict__ pc1w, const float* __restrict__ pc1b,
    const float* __restrict__ pc2w, const float* __restrict__ pc2b,
    const float* __restrict__ pr1w, const float* __restrict__ pr1b,
    const float* __restrict__ pr2w, const float* __restrict__ pr2b,
    float* __restrict__ mcls, float* __restrict__ mreg)
{
  __shared__ float rowv[256];
  __shared__ float hv[32];
  const int tid = threadIdx.x, b = blockIdx.x;
  rowv[tid] = pro[(size_t)b*256 + tid];
  __syncthreads();
  for (int br = 0; br < 2; br++){
    const float* w1 = br ? pr1w : pc1w;
    const float* b1 = br ? pr1b : pc1b;
    const float* w2 = br ? pr2w : pc2w;
    const float* b2 = br ? pr2b : pc2b;
    float* outm = br ? mreg : mcls;
    if (tid < 32){
      float s = b1[tid];
      const float* wr = w1 + tid*256;
      for (int k = 0; k < 256; k += 4)
        s += rowv[k]*wr[k] + rowv[k+1]*wr[k+1] + rowv[k+2]*wr[k+2] + rowv[k+3]*wr[k+3];
      hv[tid] = s;
    }
    __syncthreads();
    float s = b2[tid];
    const float* w2r = w2 + tid*32;
    #pragma unroll
    for (int j = 0; j < 32; j++) s += hv[j]*w2r[j];
    outm[(size_t)b*256 + tid] = 1.f/(1.f + expf(-s));
    __syncthreads();
  }
}

// ---------------- GEMM1: params[C][32768] = proB @ dynwB^T + dynbP (bf16) ----------------
// BM=128 BN=128 BK=64, double-buffered, 512 threads, 64KB LDS -> 2 blocks/CU
__global__ __launch_bounds__(512, 4) void gemm1_kernel(const u16* __restrict__ proB,
    const u16* __restrict__ dynwB, const float* __restrict__ dynbP,
    u16* __restrict__ paramsOut, int b0, int C)
{
  __shared__ u16 sm[2][2][128*64];   // [buf][A=0/B=1][128 rows][64 k]
  const int tid = threadIdx.x;
  const int bx = blockIdx.x, by = blockIdx.y;
  const int l = tid & 63, wid = tid >> 6, l15 = l & 15, lg = l >> 4;
  const int wm = wid >> 2, wn = wid & 3;   // 2 x 4 waves, wave tile 64m x 32n
  const char* Abase = (const char*)proB;
  const char* Bbase = (const char*)dynwB;

  auto stage = [&](int t, int buf){
    #pragma unroll
    for (int p = 0; p < 2; p++){
      int base = (wid + p*8)*1024;
      int lin = base + l*16;
      int row = lin >> 7, cb = lin & 127;
      int swz = (row & 7) << 4;
      GLDS16(Abase + (size_t)(b0 + bx*128 + row)*512 + t*128 + (cb ^ swz),
             (char*)sm[buf][0] + base);
      GLDS16(Bbase + (size_t)(by*128 + row)*512 + t*128 + (cb ^ swz),
             (char*)sm[buf][1] + base);
    }
  };

  f32x4 acc[4][2];
  #pragma unroll
  for (int i=0;i<4;i++){ acc[i][0]=zero4(); acc[i][1]=zero4(); }

  stage(0, 0);
  __syncthreads();
  for (int t = 0; t < 4; t++){
    if (t < 3) stage(t+1, (t&1)^1);
    const char* sa = (const char*)sm[t&1][0];
    const char* sb = (const char*)sm[t&1][1];
    #pragma unroll
    for (int ks = 0; ks < 2; ks++){
      bf16x8 av[4], bv[2];
      #pragma unroll
      for (int mt=0; mt<4; mt++){
        int row = wm*64 + mt*16 + l15;
        av[mt] = *(const bf16x8*)(sa + row*128 + ((ks*64 + lg*16) ^ ((row&7)<<4)));
      }
      #pragma unroll
      for (int nt=0; nt<2; nt++){
        int row = wn*32 + nt*16 + l15;
        bv[nt] = *(const bf16x8*)(sb + row*128 + ((ks*64 + lg*16) ^ ((row&7)<<4)));
      }
      #pragma unroll
      for (int mt=0; mt<4; mt++)
        #pragma unroll
        for (int nt=0; nt<2; nt++)
          acc[mt][nt] = mfma16(av[mt], bv[nt], acc[mt][nt]);
    }
    __syncthreads();
  }
  // epilogue: + bias, ->bf16, stage in LDS, coalesced store
  float bb[2];
  #pragma unroll
  for (int nt=0; nt<2; nt++) bb[nt] = dynbP[by*128 + wn*32 + nt*16 + l15];
  char* tile = (char*)sm;   // 32KB
  #pragma unroll
  for (int mt=0; mt<4; mt++)
    #pragma unroll
    for (int nt=0; nt<2; nt++)
      #pragma unroll
      for (int r=0; r<4; r++){
        int row = wm*64 + mt*16 + lg*4 + r;
        int col = wn*32 + nt*16 + l15;
        *(u16*)(tile + row*256 + ((col*2) ^ ((row&7)<<4))) = f2bf(acc[mt][nt][r] + bb[nt]);
      }
  __syncthreads();
  #pragma unroll
  for (int p = 0; p < 4; p++){
    int lin = (tid + p*512)*16;
    int row = lin >> 8, cb = lin & 255;
    int rg = bx*128 + row;
    if (rg < C){
      uint4 v = *(const uint4*)(tile + row*256 + (cb ^ ((row&7)<<4)));
      *(uint4*)((char*)paramsOut + (size_t)rg*65536 + (size_t)by*256 + cb) = v;
    }
  }
}

// ---------------- fused conv: x=feats@p1; LN1relu; x2=y@p2; LN2relu; mask; LN3relu ----------------
// 256 thr = 4 waves; wave w owns rows 16w..16w+15 (wave-local LN via 16-lane shfl).
// LDS 48KB -> 3 blocks/CU.
__global__ __launch_bounds__(256, 3) void conv_kernel(const float* __restrict__ roi,
    const u16* __restrict__ params,
    const float* __restrict__ n1g, const float* __restrict__ n1b,
    const float* __restrict__ n2g, const float* __restrict__ n2b,
    const float* __restrict__ n3cg, const float* __restrict__ n3cb,
    const float* __restrict__ n3rg, const float* __restrict__ n3rb,
    const float* __restrict__ mcls, const float* __restrict__ mreg,
    u16* __restrict__ fcin, u16* __restrict__ frin, int b0)
{
  __shared__ char lds[49152];
  // lds+0     : SF feats-half [64][128] swz (16K);  later SP2/out-tile (32K = lds+0..32K)
  // lds+16384 : SP1 p1-half fragment-order (16K)
  // lds+32768 : SY y [64][64] swz (8K)
  // lds+40960 : SC coefs [8][256] f32 (8K): g2,b2,g3c,b3c,g3r,b3r,mc,mr
  const int tid = threadIdx.x, bloc = blockIdx.x, b = b0 + bloc;
  const int l = tid & 63, w = tid >> 6, l15 = l & 15, lg = l >> 4;
  float* SCf = (float*)(lds + 40960);
  SCf[0*256+tid] = n2g[tid];  SCf[1*256+tid] = n2b[tid];
  SCf[2*256+tid] = n3cg[tid]; SCf[3*256+tid] = n3cb[tid];
  SCf[4*256+tid] = n3rg[tid]; SCf[5*256+tid] = n3rb[tid];
  SCf[6*256+tid] = mcls[(size_t)b*256+tid];
  SCf[7*256+tid] = mreg[(size_t)b*256+tid];

  const char* pbase = (const char*)params + (size_t)bloc*65536;
  const int myrow = 16*w + l15;           // A-frag row for this lane

  f32x4 xacc[4];
  #pragma unroll
  for (int i=0;i<4;i++) xacc[i] = zero4();

  // ---- phase 1: x = feats @ p1, K=256 in 2 halves of 128 ----
  for (int hh = 0; hh < 2; hh++){
    #pragma unroll
    for (int p = 0; p < 4; p++)
      GLDS16(pbase + p*8192 + hh*4096 + tid*16, lds + 16384 + p*4096 + w*1024);
    {
      int row = tid >> 2, ks4 = tid & 3;
      u16 tt[32];
      if (row < Tc){
        const float* s = roi + ((size_t)row*Bc + b)*256 + hh*128 + ks4*32;
        #pragma unroll
        for (int j = 0; j < 8; j++){
          float4 v = *(const float4*)(s + j*4);
          tt[j*4+0]=f2bf(v.x); tt[j*4+1]=f2bf(v.y); tt[j*4+2]=f2bf(v.z); tt[j*4+3]=f2bf(v.w);
        }
      } else {
        #pragma unroll
        for (int j=0;j<32;j++) tt[j]=0;
      }
      int swz = (row & 7) << 4;
      #pragma unroll
      for (int c = 0; c < 4; c++)
        *(uint4*)(lds + row*256 + ((ks4*64 + c*16) ^ swz)) = ((const uint4*)tt)[c];
    }
    __syncthreads();
    #pragma unroll
    for (int ks = 0; ks < 4; ks++){
      bf16x8 af = *(const bf16x8*)(lds + myrow*256 + ((ks*64 + lg*16) ^ ((myrow&7)<<4)));
      #pragma unroll
      for (int nt = 0; nt < 4; nt++){
        bf16x8 bf = *(const bf16x8*)(lds + 16384 + nt*4096 + ks*1024 + lg*256 + l15*16);
        xacc[nt] = mfma16(af, bf, xacc[nt]);
      }
    }
    __syncthreads();
  }

  // ---- stage p2 (fragment-order, 32K into lds+0) while doing LN1 ----
  #pragma unroll
  for (int p = 0; p < 8; p++)
    GLDS16(pbase + 32768 + p*4096 + tid*16, lds + p*4096 + w*1024);

  {
    float g1v[4], b1v[4];
    #pragma unroll
    for (int nt=0; nt<4; nt++){ g1v[nt] = n1g[nt*16+l15]; b1v[nt] = n1b[nt*16+l15]; }
    #pragma unroll
    for (int r = 0; r < 4; r++){
      float s = xacc[0][r]+xacc[1][r]+xacc[2][r]+xacc[3][r];
      float q = xacc[0][r]*xacc[0][r]+xacc[1][r]*xacc[1][r]
              + xacc[2][r]*xacc[2][r]+xacc[3][r]*xacc[3][r];
      #pragma unroll
      for (int m = 1; m < 16; m <<= 1){ s += __shfl_xor(s, m); q += __shfl_xor(q, m); }
      float mu = s*(1.f/64.f);
      float rs = rsqrtf(q*(1.f/64.f) - mu*mu + 1e-5f);
      int row = 16*w + lg*4 + r;
      int swz = (row & 7) << 4;
      #pragma unroll
      for (int nt=0; nt<4; nt++){
        float yv = fmaxf((xacc[nt][r]-mu)*rs*g1v[nt] + b1v[nt], 0.f);
        *(u16*)(lds + 32768 + row*128 + ((2*(nt*16+l15)) ^ swz)) = f2bf(yv);
      }
    }
  }
  __syncthreads();

  // ---- phase 2: x2 = y @ p2 (49x64 @ 64x256) ----
  f32x4 acc[16];
  #pragma unroll
  for (int i=0;i<16;i++) acc[i] = zero4();
  #pragma unroll
  for (int ks = 0; ks < 2; ks++){
    bf16x8 ay = *(const bf16x8*)(lds + 32768 + myrow*128 + ((ks*64 + lg*16) ^ ((myrow&7)<<4)));
    #pragma unroll
    for (int nt = 0; nt < 16; nt++){
      bf16x8 bp = *(const bf16x8*)(lds + nt*2048 + ks*1024 + lg*256 + l15*16);
      acc[nt] = mfma16(ay, bp, acc[nt]);
    }
  }

  // ---- LN2: stats over 256 cols, store xhat in-place ----
  float mu2[4], rs2[4];
  #pragma unroll
  for (int r = 0; r < 4; r++){
    float s = 0.f, q = 0.f;
    #pragma unroll
    for (int nt=0; nt<16; nt++){ float v = acc[nt][r]; s += v; q += v*v; }
    #pragma unroll
    for (int m = 1; m < 16; m <<= 1){ s += __shfl_xor(s, m); q += __shfl_xor(q, m); }
    float mu = s*(1.f/256.f);
    float rs = rsqrtf(q*(1.f/256.f) - mu*mu + 1e-5f);
    mu2[r] = mu; rs2[r] = rs;
    #pragma unroll
    for (int nt=0; nt<16; nt++) acc[nt][r] = (acc[nt][r]-mu)*rs;
  }
  __syncthreads();   // all waves done reading p2 -> lds+0 reusable as out-tile

  // ---- branches: u = relu(xhat*(g2*m) + b2*m); LN3; relu; -> bf16 tile; copy out ----
  for (int br = 0; br < 2; br++){
    float s3[4] = {0.f,0.f,0.f,0.f}, q3[4] = {0.f,0.f,0.f,0.f};
    #pragma unroll
    for (int nt=0; nt<16; nt++){
      int col = nt*16 + l15;
      float mv = SCf[(6+br)*256 + col];
      float gm = SCf[0*256 + col]*mv, bm = SCf[1*256 + col]*mv;
      #pragma unroll
      for (int r=0; r<4; r++){
        float u = fmaxf(acc[nt][r]*gm + bm, 0.f);
        s3[r] += u; q3[r] += u*u;
      }
    }
    float m3[4], r3[4];
    #pragma unroll
    for (int r=0; r<4; r++){
      float s = s3[r], q = q3[r];
      #pragma unroll
      for (int m = 1; m < 16; m <<= 1){ s += __shfl_xor(s, m); q += __shfl_xor(q, m); }
      float mu = s*(1.f/256.f);
      m3[r] = mu; r3[r] = rsqrtf(q*(1.f/256.f) - mu*mu + 1e-5f);
    }
    #pragma unroll
    for (int nt=0; nt<16; nt++){
      int col = nt*16 + l15;
      float mv = SCf[(6+br)*256 + col];
      float gm = SCf[0*256 + col]*mv, bm = SCf[1*256 + col]*mv;
      float g3 = SCf[(2+2*br)*256 + col], b3 = SCf[(3+2*br)*256 + col];
      #pragma unroll
      for (int r=0; r<4; r++){
        int row = 16*w + lg*4 + r;
        float u = fmaxf(acc[nt][r]*gm + bm, 0.f);
        float f = fmaxf((u - m3[r])*r3[r]*g3 + b3, 0.f);
        *(u16*)(lds + row*512 + ((2*col) ^ ((row&7)<<4))) = f2bf(f);
      }
    }
    __syncthreads();
    {
      u16* outp = (br ? frin : fcin) + (size_t)bloc * KOUT;
      #pragma unroll
      for (int p = 0; p < 7; p++){
        int lin = tid*16 + p*4096;
        if (lin < Tc*512){
          int row = lin >> 9, cb = lin & 511;
          uint4 v = *(const uint4*)(lds + row*512 + (cb ^ ((row&7)<<4)));
          *(uint4*)((char*)outp + lin) = v;
        }
      }
    }
    __syncthreads();
  }
}

// ---------------- outGEMM partial: pbuf[z][s][C][256] += fin @ W^T over K-chunk ----------------
__global__ __launch_bounds__(256, 4) void outgemm_part(
    const u16* __restrict__ fcin, const u16* __restrict__ frin,
    const u16* __restrict__ ocw, const u16* __restrict__ orw,
    float* __restrict__ pbuf, int C)
{
  __shared__ u16 smA[64*64];
  __shared__ u16 smB[256*64];
  const int tid = threadIdx.x;
  const int z = blockIdx.y, sp = blockIdx.z;
  const int m0 = blockIdx.x * 64;
  const u16* A = z ? frin : fcin;
  const u16* W = z ? orw : ocw;
  const int l = tid & 63, w = tid >> 6, l15 = l & 15, lg = l >> 4;

  f32x4 acc[4][4];
  #pragma unroll
  for (int i=0;i<4;i++)
    #pragma unroll
    for (int j=0;j<4;j++) acc[i][j] = zero4();

  for (int kt = sp*49; kt < sp*49 + 49; kt++){
    #pragma unroll
    for (int p = 0; p < 2; p++){
      int base = (w + p*4)*1024;
      int lin = base + l*16;
      int row = lin >> 7, cb = lin & 127;
      int rg = m0 + row; if (rg > C-1) rg = C-1;
      GLDS16((const char*)A + (size_t)rg*25088 + kt*128 + (cb ^ ((row & 7) << 4)), (char*)smA + base);
    }
    #pragma unroll
    for (int p = 0; p < 8; p++){
      int base = (w + p*4)*1024;
      int lin = base + l*16;
      int n = lin >> 7, cb = lin & 127;
      GLDS16((const char*)W + (size_t)n*25088 + kt*128 + (cb ^ ((n & 7) << 4)), (char*)smB + base);
    }
    __syncthreads();
    #pragma unroll
    for (int ks = 0; ks < 2; ks++){
      bf16x8 av[4], bv[4];
      #pragma unroll
      for (int mt=0; mt<4; mt++){
        int row = mt*16 + l15;
        av[mt] = *(const bf16x8*)((const char*)smA + row*128 + ((ks*64 + lg*16) ^ ((row&7)<<4)));
      }
      #pragma unroll
      for (int nt=0; nt<4; nt++){
        int row = w*64 + nt*16 + l15;
        bv[nt] = *(const bf16x8*)((const char*)smB + row*128 + ((ks*64 + lg*16) ^ ((row&7)<<4)));
      }
      #pragma unroll
      for (int mt=0; mt<4; mt++)
        #pragma unroll
        for (int nt=0; nt<4; nt++)
          acc[mt][nt] = mfma16(av[mt], bv[nt], acc[mt][nt]);
    }
    __syncthreads();
  }
  float* pb = pbuf + ((size_t)(z*4 + sp)*C)*256;
  #pragma unroll
  for (int mt=0; mt<4; mt++)
    #pragma unroll
    for (int r=0; r<4; r++){
      int row = m0 + mt*16 + lg*4 + r;
      if (row < C){
        #pragma unroll
        for (int nt=0; nt<4; nt++)
          pb[(size_t)row*256 + w*64 + nt*16 + l15] = acc[mt][nt][r];
      }
    }
}

// ---------------- LN4 finisher: sum 4 partials + bias, LN, relu -> fp32 out ----------------
__global__ __launch_bounds__(256) void ln4fin(const float* __restrict__ pbuf,
    const float* __restrict__ ocb, const float* __restrict__ orb,
    const float* __restrict__ n4cg, const float* __restrict__ n4cb,
    const float* __restrict__ n4rg, const float* __restrict__ n4rb,
    float* __restrict__ dout, int b0, int C)
{
  int R = blockIdx.x*4 + (threadIdx.x >> 6);
  if (R >= 2*C) return;
  int z = R >= C;
  int box = R - z*C;
  int lane = threadIdx.x & 63;
  int col = lane*4;
  float4 v = make_float4(0.f,0.f,0.f,0.f);
  #pragma unroll
  for (int s = 0; s < 4; s++){
    float4 p = *(const float4*)(pbuf + ((size_t)(z*4 + s)*C + box)*256 + col);
    v.x += p.x; v.y += p.y; v.z += p.z; v.w += p.w;
  }
  float4 bi = *(const float4*)((z ? orb : ocb) + col);
  v.x += bi.x; v.y += bi.y; v.z += bi.z; v.w += bi.w;
  float s = v.x+v.y+v.z+v.w;
  float q = v.x*v.x+v.y*v.y+v.z*v.z+v.w*v.w;
  #pragma unroll
  for (int m = 1; m < 64; m <<= 1){ s += __shfl_xor(s, m); q += __shfl_xor(q, m); }
  float mu = s*(1.f/256.f);
  float rs = rsqrtf(q*(1.f/256.f) - mu*mu + 1e-5f);
  float4 g = *(const float4*)((z ? n4rg : n4cg) + col);
  float4 bb = *(const float4*)((z ? n4rb : n4cb) + col);
  float4 o;
  o.x = fmaxf((v.x-mu)*rs*g.x + bb.x, 0.f);
  o.y = fmaxf((v.y-mu)*rs*g.y + bb.y, 0.f);
  o.z = fmaxf((v.z-mu)*rs*g.z + bb.z, 0.f);
  o.w = fmaxf((v.w-mu)*rs*g.w + bb.w, 0.f);
  *(float4*)(dout + (size_t)z*OUTSTRIDE + (size_t)(b0+box)*256 + col) = o;
}

extern "C" void kernel_launch(void* const* d_in, const int* in_sizes, int n_in,
                              void* d_out, int out_size, void* d_ws, size_t ws_size,
                              hipStream_t stream)
{
  (void)in_sizes; (void)n_in; (void)out_size;
  const float* pro  = (const float*)d_in[0];
  const float* roi  = (const float*)d_in[1];
  const float* dynw = (const float*)d_in[2];
  const float* dynb = (const float*)d_in[3];
  const float* n1g = (const float*)d_in[4];
  const float* n1b = (const float*)d_in[5];
  const float* n2g = (const float*)d_in[6];
  const float* n2b = (const float*)d_in[7];
  const float* pc1w = (const float*)d_in[8];
  const float* pc1b = (const float*)d_in[9];
  const float* pc2w = (const float*)d_in[10];
  const float* pc2b = (const float*)d_in[11];
  const float* n3cg = (const float*)d_in[12];
  const float* n3cb = (const float*)d_in[13];
  const float* pr1w = (const float*)d_in[14];
  const float* pr1b = (const float*)d_in[15];
  const float* pr2w = (const float*)d_in[16];
  const float* pr2b = (const float*)d_in[17];
  const float* n3rg = (const float*)d_in[18];
  const float* n3rb = (const float*)d_in[19];
  const float* ocw = (const float*)d_in[20];
  const float* ocb = (const float*)d_in[21];
  const float* n4cg = (const float*)d_in[22];
  const float* n4cb = (const float*)d_in[23];
  const float* orw = (const float*)d_in[24];
  const float* orb = (const float*)d_in[25];
  const float* n4rg = (const float*)d_in[26];
  const float* n4rb = (const float*)d_in[27];
  float* dout = (float*)d_out;

  char* ws = (char*)d_ws;
  size_t off = 0;
  auto alloc = [&](size_t bytes) -> char* {
    char* p = ws + off;
    off += (bytes + 255) & ~(size_t)255;
    return p;
  };
  u16* dynwB = (u16*)alloc((size_t)32768*256*2);
  float* dynbP = (float*)alloc((size_t)32768*4);
  u16* ocwB  = (u16*)alloc((size_t)12544*256*2);
  u16* orwB  = (u16*)alloc((size_t)12544*256*2);
  u16* proB  = (u16*)alloc((size_t)4864*256*2);
  float* mcls = (float*)alloc((size_t)4800*256*4);
  float* mreg = (float*)alloc((size_t)4800*256*4);
  size_t fixedOff = off;

  int C = 48;
  const int copts[] = {4800,2400,1600,1200,960,800,600,480,400,300,240,160,120,96,48};
  for (int i = 0; i < (int)(sizeof(copts)/sizeof(int)); i++){
    size_t need = fixedOff + (size_t)copts[i]*(65536 + 2*25088 + 8192) + 8*256;
    if (need <= ws_size){ C = copts[i]; break; }
  }
  u16* paramsC = (u16*)alloc((size_t)C*65536);
  u16* fcinC   = (u16*)alloc((size_t)C*25088);
  u16* frinC   = (u16*)alloc((size_t)C*25088);
  float* pbufC = (float*)alloc((size_t)C*8192);

  cvt_dynw_perm<<<1024, 256, 0, stream>>>(dynw, dynb, dynwB, dynbP);
  cvt_kernel<<<3136, 256, 0, stream>>>(ocw, ocwB, 12544*256);
  cvt_kernel<<<3136, 256, 0, stream>>>(orw, orwB, 12544*256);
  procvt_kernel<<<1216, 256, 0, stream>>>(pro, proB);
  masks_kernel<<<4800, 256, 0, stream>>>(pro, pc1w, pc1b, pc2w, pc2b,
                                         pr1w, pr1b, pr2w, pr2b, mcls, mreg);
  int nch = 4800 / C;
  for (int c = 0; c < nch; c++){
    int b0 = c*C;
    gemm1_kernel<<<dim3((C+127)/128, 256), 512, 0, stream>>>(proB, dynwB, dynbP, paramsC, b0, C);
    conv_kernel<<<C, 256, 0, stream>>>(roi, paramsC, n1g, n1b, n2g, n2b,
                                       n3cg, n3cb, n3rg, n3rb, mcls, mreg,
                                       fcinC, frinC, b0);
    outgemm_part<<<dim3((C+63)/64, 2, 4), 256, 0, stream>>>(fcinC, frinC, ocwB, orwB, pbufC, C);
    ln4fin<<<(2*C+3)/4, 256, 0, stream>>>(pbufC, ocb, orb, n4cg, n4cb, n4rg, n4rb, dout, b0, C);
  }
}